// Round 12
// baseline (10144.256 us; speedup 1.0000x reference)
//
#include <hip/hip_runtime.h>
#include <hip/hip_bf16.h>
#include <hip/hip_cooperative_groups.h>
#include <cstddef>

namespace cg = cooperative_groups;

typedef short bf16x8 __attribute__((ext_vector_type(8)));
typedef float f32x4 __attribute__((ext_vector_type(4)));

#define T_STEPS 512
#define BATCH   64
#define DIM     1024
#define BD      (BATCH*DIM)                   // 65536
#define IGSLOT  262144                        // f32 per ig ring slot (64ug*4096)
#define FSTRIDE 16                            // flag stride in uints (64B)

__device__ __forceinline__ float sigmoidf_(float x) { return 1.f / (1.f + __expf(-x)); }
__device__ __forceinline__ float tanhf_(float x)    { return 2.f / (1.f + __expf(-2.f * x)) - 1.f; }
__device__ __forceinline__ unsigned short f2bf(float f) {
    union { float f; unsigned int u; } v; v.f = f;
    unsigned int u = v.u + 0x7fffu + ((v.u >> 16) & 1u);
    return (unsigned short)(u >> 16);
}

// proven coherent (agent-scope, L1/L2-bypassing) 8B primitives
__device__ __forceinline__ unsigned long long coh_load8(const void* p) {
    return __hip_atomic_load((const unsigned long long*)p,
                             __ATOMIC_RELAXED, __HIP_MEMORY_SCOPE_AGENT);
}
__device__ __forceinline__ void coh_store8(void* p, unsigned long long v) {
    __hip_atomic_store((unsigned long long*)p, v,
                       __ATOMIC_RELAXED, __HIP_MEMORY_SCOPE_AGENT);
}

// 256 blocks x 256 threads. Roles of 64 blocks (ug = unit-group, 16 units each):
// role0 l0-inp: ig0[t] = W_ih0 @ x[t] + biases0     (cached f32 x reads + cvt)
// role1 l0-rec: h0[t]  = lstm(W_hh0 @ h0[t-1] + ig0[t])  (h0: write-once history)
// role2 l1-inp: ig1[t] = W_ih1 @ h0[t] + biases1    (cached h0 reads)
// role3 l1-rec: h1[t]  = lstm(W_hh1 @ h1[t-1] + ig1[t]) -> out  (h1: coh ring)
// h0 history is write-once per launch: writers store write-through (no L2 copy),
// readers first-touch lines only after the flag -> plain cached loads are fresh;
// dispatch-boundary agent acquire invalidates L2 between graph replays.
__global__ void __launch_bounds__(256, 1)
lstm_fused(const float* __restrict__ x,
           const float* __restrict__ hx,
           const float* __restrict__ cx,
           const float* __restrict__ w_ih0, const float* __restrict__ w_hh0,
           const float* __restrict__ b_ih0, const float* __restrict__ b_hh0,
           const float* __restrict__ w_ih1, const float* __restrict__ w_hh1,
           const float* __restrict__ b_ih1, const float* __restrict__ b_hh1,
           float* __restrict__ out,
           unsigned short* __restrict__ ws)
{
    // ws: h0 history[(T+1)][BD] bf16 (64.1MB), h1 ring[2][BD] bf16,
    //     ig0 ring[2][IGSLOT] f32, ig1 ring[2][IGSLOT] f32, flags[4][64*FSTRIDE]
    unsigned short* h0h = ws;                         // h0_at(t) = h0h + (t+1)*BD
    unsigned short* h1  = h0h + (size_t)(T_STEPS + 1) * BD;
    float* ig0 = (float*)(h1 + 2 * BD);
    float* ig1 = ig0 + 2 * IGSLOT;
    unsigned* flags = (unsigned*)(ig1 + 2 * IGSLOT);

    const int tid  = threadIdx.x;
    const int lane = tid & 63;
    const int wave = tid >> 6;
    const int bid  = blockIdx.x;
    const int role = bid >> 6;          // 0..3
    const int ug   = bid & 63;          // unit-group: units ug*16..ug*16+15
    const int ub   = ug * 16;

    __shared__ __align__(16) unsigned short wB[65536];      // 128 KB fragment-order weights
    __shared__ __align__(16) unsigned short hstage[64][16]; // 2 KB h repack

    // ---- stage this role's weight matrix into LDS (fragment order) ----
    {
        const float* wm = (role == 0) ? w_ih0 : (role == 1) ? w_hh0
                        : (role == 2) ? w_ih1 : w_hh1;
        for (int idx = tid; idx < 8192; idx += 256) {
            int l  = idx & 63;
            int kc = (idx >> 6) & 31;
            int n  = idx >> 11;                 // gate 0..3 (i,f,g,o)
            int c  = l & 15, kq = l >> 4;
            const float* src = wm + (size_t)(n * DIM + ub + c) * DIM + kc * 32 + kq * 8;
            float4 v0 = *(const float4*)(src);
            float4 v1 = *(const float4*)(src + 4);
            unsigned short o[8];
            o[0]=f2bf(v0.x); o[1]=f2bf(v0.y); o[2]=f2bf(v0.z); o[3]=f2bf(v0.w);
            o[4]=f2bf(v1.x); o[5]=f2bf(v1.y); o[6]=f2bf(v1.z); o[7]=f2bf(v1.w);
            *(bf16x8*)(&wB[(size_t)idx * 8]) = *(const bf16x8*)o;
        }
    }

    // ---- h[-1] init (plain stores; grid.sync's release publishes to MALL) ----
    if (role == 1 || role == 3) {
        unsigned short* hdst = (role == 1) ? h0h : (h1 + 1 * BD);
        const float* hsrc = hx + (size_t)(role >> 1) * BD;
        for (int e = tid; e < 1024; e += 256) {       // 64 rows x 16 units
            int row = e >> 4, uu = e & 15;
            hdst[row * DIM + ub + uu] = f2bf(hsrc[row * DIM + ub + uu]);
        }
    }

    // ---- zero own flag ----
    if (tid == 0)
        __hip_atomic_store(flags + (size_t)((role << 6) | ug) * FSTRIDE, 0u,
                           __ATOMIC_RELAXED, __HIP_MEMORY_SCOPE_AGENT);

    const int col  = lane & 15;      // unit (N) index within tile
    const int quad = lane >> 4;

    // biases for producer roles (full layer bias baked into ig)
    float biasv[4] = {0.f, 0.f, 0.f, 0.f};
    if (role == 0 || role == 2) {
        const float* bi = (role == 0) ? b_ih0 : b_ih1;
        const float* bh = (role == 0) ? b_hh0 : b_hh1;
        #pragma unroll
        for (int n = 0; n < 4; ++n) {
            int row = n * DIM + ub + col;
            biasv[n] = bi[row] + bh[row];
        }
    }

    // c-state for rec roles (all lanes active; 4 batch rows each)
    float creg[4] = {0.f, 0.f, 0.f, 0.f};
    if (role == 1 || role == 3) {
        const float* csrc = cx + (size_t)(role >> 1) * BD;
        #pragma unroll
        for (int r = 0; r < 4; ++r) {
            int m = wave * 16 + quad * 4 + r;
            creg[r] = csrc[m * DIM + ub + col];
        }
    }

    cg::grid_group grid = cg::this_grid();
    __syncthreads();
    grid.sync();   // release: weight/h-init/flag zeros visible below coherence point

    const int arow = wave * 16 + col;   // A-fragment batch row

    auto poll_ge = [&](const unsigned* f, int target) {
        while ((int)__hip_atomic_load(f, __ATOMIC_RELAXED, __HIP_MEMORY_SCOPE_AGENT) < target)
            __builtin_amdgcn_s_sleep(1);
    };
    auto Fp = [&](int set, int idx) -> unsigned* {
        return flags + (size_t)((set << 6) | idx) * FSTRIDE;
    };
    auto publish = [&](int set, int idx, int val) {
        __hip_atomic_store(Fp(set, idx), (unsigned)val,
                           __ATOMIC_RELAXED, __HIP_MEMORY_SCOPE_AGENT);
    };
    auto h0_at = [&](int t) -> unsigned short* {
        return h0h + (size_t)(t + 1) * BD;
    };

    // f32-input GEMM (role0: cached x reads + in-register RNE cvt)
    auto gemm_x = [&](const float* Ap,
                      f32x4& A0, f32x4& A1, f32x4& A2, f32x4& A3) {
        const float* Abase = Ap + (size_t)arow * DIM + quad * 8;
        #pragma unroll 4
        for (int kc = 0; kc < 32; ++kc) {
            float4 v0 = *(const float4*)(Abase + kc * 32);
            float4 v1 = *(const float4*)(Abase + kc * 32 + 4);
            unsigned short o[8];
            o[0]=f2bf(v0.x); o[1]=f2bf(v0.y); o[2]=f2bf(v0.z); o[3]=f2bf(v0.w);
            o[4]=f2bf(v1.x); o[5]=f2bf(v1.y); o[6]=f2bf(v1.z); o[7]=f2bf(v1.w);
            bf16x8 a = *(const bf16x8*)o;
            bf16x8 b0 = *(const bf16x8*)(&wB[((size_t)(0*32 + kc)*64 + lane)*8]);
            bf16x8 b1 = *(const bf16x8*)(&wB[((size_t)(1*32 + kc)*64 + lane)*8]);
            bf16x8 b2 = *(const bf16x8*)(&wB[((size_t)(2*32 + kc)*64 + lane)*8]);
            bf16x8 b3 = *(const bf16x8*)(&wB[((size_t)(3*32 + kc)*64 + lane)*8]);
            A0 = __builtin_amdgcn_mfma_f32_16x16x32_bf16(a, b0, A0, 0, 0, 0);
            A1 = __builtin_amdgcn_mfma_f32_16x16x32_bf16(a, b1, A1, 0, 0, 0);
            A2 = __builtin_amdgcn_mfma_f32_16x16x32_bf16(a, b2, A2, 0, 0, 0);
            A3 = __builtin_amdgcn_mfma_f32_16x16x32_bf16(a, b3, A3, 0, 0, 0);
        }
    };

    // cached-A GEMM (plain 16B loads; safe on write-once h0 history),
    // optional coherent ig preload (wave-contiguous transposed layout)
    auto gemm_cached = [&](const unsigned short* Ap, const float* igb,
                           f32x4& A0, f32x4& A1, f32x4& A2, f32x4& A3) {
        const unsigned short* Abase = Ap + (size_t)arow * DIM + quad * 8;
        if (igb) {
            union { f32x4 v; unsigned long long q[2]; } g0, g1, g2, g3;
            g0.q[0] = coh_load8(igb + 0*128); g0.q[1] = coh_load8(igb + 1*128);
            g1.q[0] = coh_load8(igb + 2*128); g1.q[1] = coh_load8(igb + 3*128);
            g2.q[0] = coh_load8(igb + 4*128); g2.q[1] = coh_load8(igb + 5*128);
            g3.q[0] = coh_load8(igb + 6*128); g3.q[1] = coh_load8(igb + 7*128);
            A0 = g0.v; A1 = g1.v; A2 = g2.v; A3 = g3.v;
        }
        #pragma unroll 8
        for (int kc = 0; kc < 32; ++kc) {
            bf16x8 a  = *(const bf16x8*)(Abase + kc * 32);
            bf16x8 b0 = *(const bf16x8*)(&wB[((size_t)(0*32 + kc)*64 + lane)*8]);
            bf16x8 b1 = *(const bf16x8*)(&wB[((size_t)(1*32 + kc)*64 + lane)*8]);
            bf16x8 b2 = *(const bf16x8*)(&wB[((size_t)(2*32 + kc)*64 + lane)*8]);
            bf16x8 b3 = *(const bf16x8*)(&wB[((size_t)(3*32 + kc)*64 + lane)*8]);
            A0 = __builtin_amdgcn_mfma_f32_16x16x32_bf16(a, b0, A0, 0, 0, 0);
            A1 = __builtin_amdgcn_mfma_f32_16x16x32_bf16(a, b1, A1, 0, 0, 0);
            A2 = __builtin_amdgcn_mfma_f32_16x16x32_bf16(a, b2, A2, 0, 0, 0);
            A3 = __builtin_amdgcn_mfma_f32_16x16x32_bf16(a, b3, A3, 0, 0, 0);
        }
    };

    // coherent-A GEMM (role3: h1 ring reuses addresses -> must bypass L2)
    auto gemm_coh = [&](const unsigned short* Ap, const float* igb,
                        f32x4& A0, f32x4& A1, f32x4& A2, f32x4& A3) {
        const unsigned short* Abase = Ap + (size_t)arow * DIM + quad * 8;
        if (igb) {
            union { f32x4 v; unsigned long long q[2]; } g0, g1, g2, g3;
            g0.q[0] = coh_load8(igb + 0*128); g0.q[1] = coh_load8(igb + 1*128);
            g1.q[0] = coh_load8(igb + 2*128); g1.q[1] = coh_load8(igb + 3*128);
            g2.q[0] = coh_load8(igb + 4*128); g2.q[1] = coh_load8(igb + 5*128);
            g3.q[0] = coh_load8(igb + 6*128); g3.q[1] = coh_load8(igb + 7*128);
            A0 = g0.v; A1 = g1.v; A2 = g2.v; A3 = g3.v;
        }
        union U { bf16x8 v; unsigned long long q[2]; };
        U pre[8];
        #pragma unroll
        for (int i = 0; i < 8; ++i) {
            pre[i].q[0] = coh_load8(Abase + i * 32);
            pre[i].q[1] = coh_load8(Abase + i * 32 + 4);
        }
        #pragma unroll
        for (int kc = 0; kc < 32; ++kc) {
            U cur = pre[kc & 7];
            if (kc < 24) {
                pre[kc & 7].q[0] = coh_load8(Abase + (kc + 8) * 32);
                pre[kc & 7].q[1] = coh_load8(Abase + (kc + 8) * 32 + 4);
            }
            bf16x8 b0 = *(const bf16x8*)(&wB[((size_t)(0*32 + kc)*64 + lane)*8]);
            bf16x8 b1 = *(const bf16x8*)(&wB[((size_t)(1*32 + kc)*64 + lane)*8]);
            bf16x8 b2 = *(const bf16x8*)(&wB[((size_t)(2*32 + kc)*64 + lane)*8]);
            bf16x8 b3 = *(const bf16x8*)(&wB[((size_t)(3*32 + kc)*64 + lane)*8]);
            A0 = __builtin_amdgcn_mfma_f32_16x16x32_bf16(cur.v, b0, A0, 0, 0, 0);
            A1 = __builtin_amdgcn_mfma_f32_16x16x32_bf16(cur.v, b1, A1, 0, 0, 0);
            A2 = __builtin_amdgcn_mfma_f32_16x16x32_bf16(cur.v, b2, A2, 0, 0, 0);
            A3 = __builtin_amdgcn_mfma_f32_16x16x32_bf16(cur.v, b3, A3, 0, 0, 0);
        }
    };

    // producer epilogue: wave-contiguous q-word layout [ug][wave][q(8)][lane]
    auto dump_ig = [&](float* slot, int set, int t,
                       f32x4 A0, f32x4 A1, f32x4 A2, f32x4 A3) {
        float* base = slot + (size_t)ug * 4096 + (size_t)wave * 1024 + lane * 2;
        union { f32x4 v; unsigned long long q[2]; } u0, u1, u2, u3;
        u0.v = A0; u1.v = A1; u2.v = A2; u3.v = A3;
        coh_store8(base + 0*128, u0.q[0]); coh_store8(base + 1*128, u0.q[1]);
        coh_store8(base + 2*128, u1.q[0]); coh_store8(base + 3*128, u1.q[1]);
        coh_store8(base + 4*128, u2.q[0]); coh_store8(base + 5*128, u2.q[1]);
        coh_store8(base + 6*128, u3.q[0]); coh_store8(base + 7*128, u3.q[1]);
        asm volatile("s_waitcnt vmcnt(0)" ::: "memory");
        __syncthreads();
        if (tid == 0) publish(set, ug, t + 1);
    };

    for (int t = 0; t < T_STEPS; ++t) {
        f32x4 A0, A1, A2, A3;

        if (role == 0) {            // ---------- l0-inp ----------
            if (tid == 0) poll_ge(Fp(1, ug), t - 1);          // ig0 slot t&1 free
            __syncthreads();
            A0 = f32x4{biasv[0], biasv[0], biasv[0], biasv[0]};
            A1 = f32x4{biasv[1], biasv[1], biasv[1], biasv[1]};
            A2 = f32x4{biasv[2], biasv[2], biasv[2], biasv[2]};
            A3 = f32x4{biasv[3], biasv[3], biasv[3], biasv[3]};
            gemm_x(x + (size_t)t * BD, A0, A1, A2, A3);
            dump_ig(ig0 + (size_t)(t & 1) * IGSLOT, 0, t, A0, A1, A2, A3);

        } else if (role == 2) {     // ---------- l1-inp ----------
            if (tid < 64) poll_ge(Fp(1, tid), t + 1);         // h0[t] ready (all)
            else if (tid == 64) poll_ge(Fp(3, ug), t - 1);    // ig1 slot t&1 free
            __syncthreads();
            A0 = f32x4{biasv[0], biasv[0], biasv[0], biasv[0]};
            A1 = f32x4{biasv[1], biasv[1], biasv[1], biasv[1]};
            A2 = f32x4{biasv[2], biasv[2], biasv[2], biasv[2]};
            A3 = f32x4{biasv[3], biasv[3], biasv[3], biasv[3]};
            gemm_cached(h0_at(t), nullptr, A0, A1, A2, A3);
            dump_ig(ig1 + (size_t)(t & 1) * IGSLOT, 2, t, A0, A1, A2, A3);

        } else if (role == 1) {     // ---------- l0-rec ----------
            if (tid < 64) poll_ge(Fp(1, tid), t);             // peers' h0[t-1]
            else if (tid == 64) poll_ge(Fp(0, ug), t + 1);    // ig0[t] ready
            __syncthreads();

            const float* igb = ig0 + (size_t)(t & 1) * IGSLOT
                             + (size_t)ug * 4096 + (size_t)wave * 1024 + lane * 2;
            gemm_cached(h0_at(t - 1), igb, A0, A1, A2, A3);

            float hreg[4];
            #pragma unroll
            for (int r = 0; r < 4; ++r) {
                float ig_ = sigmoidf_(A0[r]);
                float fg_ = sigmoidf_(A1[r]);
                float gg_ = tanhf_(A2[r]);
                float og_ = sigmoidf_(A3[r]);
                float c   = fg_ * creg[r] + ig_ * gg_;
                creg[r]   = c;
                float h   = og_ * tanhf_(c);
                hreg[r]   = h;
                int m = wave * 16 + quad * 4 + r;
                hstage[m][col] = f2bf(h);
            }
            __syncthreads();                        // hstage complete
            unsigned short* hout = h0_at(t);
            if (wave == 0) {                        // 32B/lane write-through
                const unsigned long long* src = (const unsigned long long*)&hstage[lane][0];
                unsigned long long v0 = src[0], v1 = src[1], v2 = src[2], v3 = src[3];
                unsigned short* dst = hout + (size_t)lane * DIM + ub;
                coh_store8(dst + 0,  v0);
                coh_store8(dst + 4,  v1);
                coh_store8(dst + 8,  v2);
                coh_store8(dst + 12, v3);
                asm volatile("s_waitcnt vmcnt(0)" ::: "memory");
                if (tid == 0) publish(1, ug, t + 1);
            }
            if (t == T_STEPS - 1) {
                #pragma unroll
                for (int r = 0; r < 4; ++r) {
                    int m = wave * 16 + quad * 4 + r;
                    out[(size_t)T_STEPS * BD + 0 * BD + m * DIM + ub + col] = hreg[r];
                    out[(size_t)T_STEPS * BD + 2 * BD + m * DIM + ub + col] = creg[r];
                }
            }

        } else {                    // ---------- l1-rec ----------
            if (tid < 64) poll_ge(Fp(3, tid), t);             // peers' h1[t-1]
            else if (tid == 64) poll_ge(Fp(2, ug), t + 1);    // ig1[t] ready
            __syncthreads();

            const float* igb = ig1 + (size_t)(t & 1) * IGSLOT
                             + (size_t)ug * 4096 + (size_t)wave * 1024 + lane * 2;
            gemm_coh(h1 + (size_t)((t - 1) & 1) * BD, igb, A0, A1, A2, A3);

            float hreg[4];
            #pragma unroll
            for (int r = 0; r < 4; ++r) {
                float ig_ = sigmoidf_(A0[r]);
                float fg_ = sigmoidf_(A1[r]);
                float gg_ = tanhf_(A2[r]);
                float og_ = sigmoidf_(A3[r]);
                float c   = fg_ * creg[r] + ig_ * gg_;
                creg[r]   = c;
                float h   = og_ * tanhf_(c);
                hreg[r]   = h;
                int m = wave * 16 + quad * 4 + r;
                hstage[m][col] = f2bf(h);
            }
            __syncthreads();                        // hstage complete
            unsigned short* hout = h1 + (size_t)(t & 1) * BD;
            if (wave == 0) {                        // 32B/lane write-through
                const unsigned long long* src = (const unsigned long long*)&hstage[lane][0];
                unsigned long long v0 = src[0], v1 = src[1], v2 = src[2], v3 = src[3];
                unsigned short* dst = hout + (size_t)lane * DIM + ub;
                coh_store8(dst + 0,  v0);
                coh_store8(dst + 4,  v1);
                coh_store8(dst + 8,  v2);
                coh_store8(dst + 12, v3);
                asm volatile("s_waitcnt vmcnt(0)" ::: "memory");
                if (tid == 0) publish(3, ug, t + 1);
            }

            // off-critical-path output stores
            #pragma unroll
            for (int r = 0; r < 4; ++r) {
                int m = wave * 16 + quad * 4 + r;
                out[(size_t)t * BD + (size_t)m * DIM + ub + col] = hreg[r];
                if (t == T_STEPS - 1) {
                    out[(size_t)T_STEPS * BD + 1 * BD + m * DIM + ub + col] = hreg[r];
                    out[(size_t)T_STEPS * BD + 3 * BD + m * DIM + ub + col] = creg[r];
                }
            }
        }
    }
}

extern "C" void kernel_launch(void* const* d_in, const int* in_sizes, int n_in,
                              void* d_out, int out_size, void* d_ws, size_t ws_size,
                              hipStream_t stream) {
    const float* x     = (const float*)d_in[0];
    const float* hx    = (const float*)d_in[1];
    const float* cx    = (const float*)d_in[2];
    const float* w_ih0 = (const float*)d_in[3];
    const float* w_hh0 = (const float*)d_in[4];
    const float* b_ih0 = (const float*)d_in[5];
    const float* b_hh0 = (const float*)d_in[6];
    const float* w_ih1 = (const float*)d_in[7];
    const float* w_hh1 = (const float*)d_in[8];
    const float* b_ih1 = (const float*)d_in[9];
    const float* b_hh1 = (const float*)d_in[10];
    float* outp = (float*)d_out;
    unsigned short* wsp = (unsigned short*)d_ws;

    void* args[] = { &x, &hx, &cx, &w_ih0, &w_hh0, &b_ih0, &b_hh0,
                     &w_ih1, &w_hh1, &b_ih1, &b_hh1, &outp, &wsp };
    hipLaunchCooperativeKernel((void*)lstm_fused, dim3(256), dim3(256),
                               args, 0, stream);
}

// Round 13
// 4005.827 us; speedup vs baseline: 2.5324x; 2.5324x over previous
//
#include <hip/hip_runtime.h>
#include <hip/hip_bf16.h>
#include <hip/hip_cooperative_groups.h>
#include <cstddef>

namespace cg = cooperative_groups;

typedef short bf16x8 __attribute__((ext_vector_type(8)));
typedef float f32x4 __attribute__((ext_vector_type(4)));

#define T_STEPS 512
#define BATCH   64
#define DIM     1024
#define BD      (BATCH*DIM)                   // 65536
#define XB_ELEMS ((size_t)T_STEPS*BATCH*DIM)  // 33554432
#define IGSLOT  262144                        // f32 per ig ring slot (64ug*4096)
#define FSTRIDE 16                            // flag stride in uints (64B)

__device__ __forceinline__ float sigmoidf_(float x) { return 1.f / (1.f + __expf(-x)); }
__device__ __forceinline__ float tanhf_(float x)    { return 2.f / (1.f + __expf(-2.f * x)) - 1.f; }
__device__ __forceinline__ unsigned short f2bf(float f) {
    union { float f; unsigned int u; } v; v.f = f;
    unsigned int u = v.u + 0x7fffu + ((v.u >> 16) & 1u);
    return (unsigned short)(u >> 16);
}

// proven coherent (agent-scope, L1/L2-bypassing) 8B primitives
__device__ __forceinline__ unsigned long long coh_load8(const void* p) {
    return __hip_atomic_load((const unsigned long long*)p,
                             __ATOMIC_RELAXED, __HIP_MEMORY_SCOPE_AGENT);
}
__device__ __forceinline__ void coh_store8(void* p, unsigned long long v) {
    __hip_atomic_store((unsigned long long*)p, v,
                       __ATOMIC_RELAXED, __HIP_MEMORY_SCOPE_AGENT);
}

// 256 blocks x 256 threads. Roles of 64 blocks (ug = unit-group, 16 units each):
// role0 l0-inp: ig0[t] = W_ih0 @ xb[t] + biases0    (cached xb reads, runs ahead)
// role1 l0-rec: h0[t]  = lstm(W_hh0 @ h0[t-1] + ig0[t])
// role2 l1-inp: ig1[t] = W_ih1 @ h0[t] + biases1    (coherent h0 reads)
// role3 l1-rec: h1[t]  = lstm(W_hh1 @ h1[t-1] + ig1[t]) -> out
//
// h slots are stored FRAGMENT-MAJOR: element (row m, dim d) lives at
//   (d>>5)*2048 + m*32 + (d&31)   (bf16 elems within the 128KB slot)
// so a consumer wave's A-fragment load instruction covers a contiguous 512B
// (64 lanes x 8B, fully-used lines) instead of 16 rows 2KB apart.
__global__ void __launch_bounds__(256, 1)
lstm_fused(const float* __restrict__ x,
           const float* __restrict__ hx,
           const float* __restrict__ cx,
           const float* __restrict__ w_ih0, const float* __restrict__ w_hh0,
           const float* __restrict__ b_ih0, const float* __restrict__ b_hh0,
           const float* __restrict__ w_ih1, const float* __restrict__ w_hh1,
           const float* __restrict__ b_ih1, const float* __restrict__ b_hh1,
           float* __restrict__ out,
           unsigned short* __restrict__ ws)
{
    // ws: xb[T][B][DIM] bf16, h0 ring[4][BD] bf16, h1 ring[2][BD] bf16,
    //     ig0 ring[2][IGSLOT] f32, ig1 ring[2][IGSLOT] f32, flags[4][64*FSTRIDE]
    unsigned short* xb = ws;
    unsigned short* h0 = ws + XB_ELEMS;
    unsigned short* h1 = h0 + 4 * BD;
    float* ig0 = (float*)(h1 + 2 * BD);
    float* ig1 = ig0 + 2 * IGSLOT;
    unsigned* flags = (unsigned*)(ig1 + 2 * IGSLOT);

    const int tid  = threadIdx.x;
    const int lane = tid & 63;
    const int wave = tid >> 6;
    const int bid  = blockIdx.x;
    const int role = bid >> 6;          // 0..3
    const int ug   = bid & 63;          // unit-group: units ug*16..ug*16+15
    const int ub   = ug * 16;

    __shared__ __align__(16) unsigned short wB[65536];      // 128 KB fragment-order weights
    __shared__ __align__(16) unsigned short hstage[64][16]; // 2 KB h repack

    // ---- stage this role's weight matrix into LDS (fragment order) ----
    {
        const float* wm = (role == 0) ? w_ih0 : (role == 1) ? w_hh0
                        : (role == 2) ? w_ih1 : w_hh1;
        for (int idx = tid; idx < 8192; idx += 256) {
            int l  = idx & 63;
            int kc = (idx >> 6) & 31;
            int n  = idx >> 11;                 // gate 0..3 (i,f,g,o)
            int c  = l & 15, kq = l >> 4;
            const float* src = wm + (size_t)(n * DIM + ub + c) * DIM + kc * 32 + kq * 8;
            float4 v0 = *(const float4*)(src);
            float4 v1 = *(const float4*)(src + 4);
            unsigned short o[8];
            o[0]=f2bf(v0.x); o[1]=f2bf(v0.y); o[2]=f2bf(v0.z); o[3]=f2bf(v0.w);
            o[4]=f2bf(v1.x); o[5]=f2bf(v1.y); o[6]=f2bf(v1.z); o[7]=f2bf(v1.w);
            *(bf16x8*)(&wB[(size_t)idx * 8]) = *(const bf16x8*)o;
        }
    }

    // ---- cast x to bf16 (grid-stride, all blocks; xb stays row-major) ----
    {
        const int nthr = 256 * gridDim.x;
        const int gtid = bid * 256 + tid;
        const float4* xv = (const float4*)x;
        const int n4 = (int)(XB_ELEMS / 4);
        for (int i = gtid; i < n4; i += nthr) {
            float4 v = xv[i];
            ushort4 o;
            o.x=f2bf(v.x); o.y=f2bf(v.y); o.z=f2bf(v.z); o.w=f2bf(v.w);
            *(ushort4*)(xb + (size_t)i * 4) = o;
        }
    }

    // ---- h[-1] into ring, fragment layout (l0: slot 3; l1: slot 1) ----
    if (role == 1 || role == 3) {
        unsigned short* hdst = (role == 1) ? (h0 + 3 * BD) : (h1 + 1 * BD);
        const float* hsrc = hx + (size_t)(role >> 1) * BD;
        const int kcp = ub >> 5, sub = ub & 31;
        for (int e = tid; e < 1024; e += 256) {       // 64 rows x 16 units
            int row = e >> 4, uu = e & 15;
            hdst[kcp * 2048 + row * 32 + sub + uu] = f2bf(hsrc[row * DIM + ub + uu]);
        }
    }

    // ---- zero own flag ----
    if (tid == 0)
        __hip_atomic_store(flags + (size_t)((role << 6) | ug) * FSTRIDE, 0u,
                           __ATOMIC_RELAXED, __HIP_MEMORY_SCOPE_AGENT);

    const int col  = lane & 15;      // unit (N) index within tile
    const int quad = lane >> 4;

    // biases for producer roles (full layer bias baked into ig)
    float biasv[4] = {0.f, 0.f, 0.f, 0.f};
    if (role == 0 || role == 2) {
        const float* bi = (role == 0) ? b_ih0 : b_ih1;
        const float* bh = (role == 0) ? b_hh0 : b_hh1;
        #pragma unroll
        for (int n = 0; n < 4; ++n) {
            int row = n * DIM + ub + col;
            biasv[n] = bi[row] + bh[row];
        }
    }

    // c-state for rec roles (all lanes active; 4 batch rows each)
    float creg[4] = {0.f, 0.f, 0.f, 0.f};
    if (role == 1 || role == 3) {
        const float* csrc = cx + (size_t)(role >> 1) * BD;
        #pragma unroll
        for (int r = 0; r < 4; ++r) {
            int m = wave * 16 + quad * 4 + r;
            creg[r] = csrc[m * DIM + ub + col];
        }
    }

    cg::grid_group grid = cg::this_grid();
    __syncthreads();
    grid.sync();   // release: xb / h-init / flag zeros visible below coherence point

    const int arow = wave * 16 + col;   // A-fragment batch row

    auto poll_ge = [&](const unsigned* f, int target) {
        while ((int)__hip_atomic_load(f, __ATOMIC_RELAXED, __HIP_MEMORY_SCOPE_AGENT) < target)
            __builtin_amdgcn_s_sleep(1);
    };
    auto Fp = [&](int set, int idx) -> unsigned* {
        return flags + (size_t)((set << 6) | idx) * FSTRIDE;
    };
    auto publish = [&](int set, int idx, int val) {
        __hip_atomic_store(Fp(set, idx), (unsigned)val,
                           __ATOMIC_RELAXED, __HIP_MEMORY_SCOPE_AGENT);
    };

    // plain-load GEMM (cached A: xb path, row-major), 4 gate N-tiles
    auto gemm_plain = [&](const unsigned short* Ap,
                          f32x4& A0, f32x4& A1, f32x4& A2, f32x4& A3) {
        const unsigned short* Abase = Ap + (size_t)arow * DIM + quad * 8;
        #pragma unroll 8
        for (int kc = 0; kc < 32; ++kc) {
            bf16x8 a  = *(const bf16x8*)(Abase + kc * 32);
            bf16x8 b0 = *(const bf16x8*)(&wB[((size_t)(0*32 + kc)*64 + lane)*8]);
            bf16x8 b1 = *(const bf16x8*)(&wB[((size_t)(1*32 + kc)*64 + lane)*8]);
            bf16x8 b2 = *(const bf16x8*)(&wB[((size_t)(2*32 + kc)*64 + lane)*8]);
            bf16x8 b3 = *(const bf16x8*)(&wB[((size_t)(3*32 + kc)*64 + lane)*8]);
            A0 = __builtin_amdgcn_mfma_f32_16x16x32_bf16(a, b0, A0, 0, 0, 0);
            A1 = __builtin_amdgcn_mfma_f32_16x16x32_bf16(a, b1, A1, 0, 0, 0);
            A2 = __builtin_amdgcn_mfma_f32_16x16x32_bf16(a, b2, A2, 0, 0, 0);
            A3 = __builtin_amdgcn_mfma_f32_16x16x32_bf16(a, b3, A3, 0, 0, 0);
        }
    };

    // coherent-A GEMM on FRAGMENT-MAJOR h: lane address = arow*32 + quad*8,
    // kc stride 2048 -> each load instruction is a contiguous 512B per wave.
    // 8-deep rolling prefetch; optional coherent ig preload (wave-contig layout).
    auto gemm_coh = [&](const unsigned short* Ap, const float* igb,
                        f32x4& A0, f32x4& A1, f32x4& A2, f32x4& A3) {
        const unsigned short* Abase = Ap + (size_t)arow * 32 + quad * 8;
        if (igb) {
            union { f32x4 v; unsigned long long q[2]; } g0, g1, g2, g3;
            g0.q[0] = coh_load8(igb + 0*128); g0.q[1] = coh_load8(igb + 1*128);
            g1.q[0] = coh_load8(igb + 2*128); g1.q[1] = coh_load8(igb + 3*128);
            g2.q[0] = coh_load8(igb + 4*128); g2.q[1] = coh_load8(igb + 5*128);
            g3.q[0] = coh_load8(igb + 6*128); g3.q[1] = coh_load8(igb + 7*128);
            A0 = g0.v; A1 = g1.v; A2 = g2.v; A3 = g3.v;
        }
        union U { bf16x8 v; unsigned long long q[2]; };
        U pre[8];
        #pragma unroll
        for (int i = 0; i < 8; ++i) {
            pre[i].q[0] = coh_load8(Abase + (size_t)i * 2048);
            pre[i].q[1] = coh_load8(Abase + (size_t)i * 2048 + 4);
        }
        #pragma unroll
        for (int kc = 0; kc < 32; ++kc) {
            U cur = pre[kc & 7];
            if (kc < 24) {
                pre[kc & 7].q[0] = coh_load8(Abase + (size_t)(kc + 8) * 2048);
                pre[kc & 7].q[1] = coh_load8(Abase + (size_t)(kc + 8) * 2048 + 4);
            }
            bf16x8 b0 = *(const bf16x8*)(&wB[((size_t)(0*32 + kc)*64 + lane)*8]);
            bf16x8 b1 = *(const bf16x8*)(&wB[((size_t)(1*32 + kc)*64 + lane)*8]);
            bf16x8 b2 = *(const bf16x8*)(&wB[((size_t)(2*32 + kc)*64 + lane)*8]);
            bf16x8 b3 = *(const bf16x8*)(&wB[((size_t)(3*32 + kc)*64 + lane)*8]);
            A0 = __builtin_amdgcn_mfma_f32_16x16x32_bf16(cur.v, b0, A0, 0, 0, 0);
            A1 = __builtin_amdgcn_mfma_f32_16x16x32_bf16(cur.v, b1, A1, 0, 0, 0);
            A2 = __builtin_amdgcn_mfma_f32_16x16x32_bf16(cur.v, b2, A2, 0, 0, 0);
            A3 = __builtin_amdgcn_mfma_f32_16x16x32_bf16(cur.v, b3, A3, 0, 0, 0);
        }
    };

    // producer epilogue: wave-contiguous q-word layout [ug][wave][q(8)][lane]
    auto dump_ig = [&](float* slot, int set, int t,
                       f32x4 A0, f32x4 A1, f32x4 A2, f32x4 A3) {
        float* base = slot + (size_t)ug * 4096 + (size_t)wave * 1024 + lane * 2;
        union { f32x4 v; unsigned long long q[2]; } u0, u1, u2, u3;
        u0.v = A0; u1.v = A1; u2.v = A2; u3.v = A3;
        coh_store8(base + 0*128, u0.q[0]); coh_store8(base + 1*128, u0.q[1]);
        coh_store8(base + 2*128, u1.q[0]); coh_store8(base + 3*128, u1.q[1]);
        coh_store8(base + 4*128, u2.q[0]); coh_store8(base + 5*128, u2.q[1]);
        coh_store8(base + 6*128, u3.q[0]); coh_store8(base + 7*128, u3.q[1]);
        asm volatile("s_waitcnt vmcnt(0)" ::: "memory");
        __syncthreads();
        if (tid == 0) publish(set, ug, t + 1);
    };

    const int kcp = ub >> 5, sub = ub & 31;   // this ug's fragment chunk

    for (int t = 0; t < T_STEPS; ++t) {
        f32x4 A0, A1, A2, A3;

        if (role == 0) {            // ---------- l0-inp ----------
            if (tid == 0) poll_ge(Fp(1, ug), t - 1);          // ig0 slot t&1 free
            __syncthreads();
            A0 = f32x4{biasv[0], biasv[0], biasv[0], biasv[0]};
            A1 = f32x4{biasv[1], biasv[1], biasv[1], biasv[1]};
            A2 = f32x4{biasv[2], biasv[2], biasv[2], biasv[2]};
            A3 = f32x4{biasv[3], biasv[3], biasv[3], biasv[3]};
            gemm_plain(xb + (size_t)t * BD, A0, A1, A2, A3);
            dump_ig(ig0 + (size_t)(t & 1) * IGSLOT, 0, t, A0, A1, A2, A3);

        } else if (role == 2) {     // ---------- l1-inp ----------
            if (tid < 64) poll_ge(Fp(1, tid), t + 1);         // h0[t] ready (all)
            else if (tid == 64) poll_ge(Fp(3, ug), t - 1);    // ig1 slot t&1 free
            __syncthreads();
            A0 = f32x4{biasv[0], biasv[0], biasv[0], biasv[0]};
            A1 = f32x4{biasv[1], biasv[1], biasv[1], biasv[1]};
            A2 = f32x4{biasv[2], biasv[2], biasv[2], biasv[2]};
            A3 = f32x4{biasv[3], biasv[3], biasv[3], biasv[3]};
            gemm_coh(h0 + (size_t)(t & 3) * BD, nullptr, A0, A1, A2, A3);
            dump_ig(ig1 + (size_t)(t & 1) * IGSLOT, 2, t, A0, A1, A2, A3);

        } else {                    // ---------- rec roles ----------
            if (role == 1) {
                if (tid < 64) poll_ge(Fp(1, tid), t);                 // peers' h0[t-1]
                else if (tid < 128) poll_ge(Fp(2, tid - 64), t - 3);  // h0 slot t&3 free
                else if (tid == 128) poll_ge(Fp(0, ug), t + 1);       // ig0[t] ready
            } else {
                if (tid < 64) poll_ge(Fp(3, tid), t);                 // peers' h1[t-1]
                else if (tid == 64) poll_ge(Fp(2, ug), t + 1);        // ig1[t] ready
            }
            __syncthreads();

            unsigned short* hring = (role == 1) ? h0 : h1;
            const unsigned short* hsrc = (role == 1)
                ? (h0 + (size_t)((t - 1) & 3) * BD)
                : (h1 + (size_t)((t - 1) & 1) * BD);
            const float* igb = ((role == 1) ? ig0 : ig1) + (size_t)(t & 1) * IGSLOT
                             + (size_t)ug * 4096 + (size_t)wave * 1024 + lane * 2;
            gemm_coh(hsrc, igb, A0, A1, A2, A3);

            float hreg[4];
            #pragma unroll
            for (int r = 0; r < 4; ++r) {
                float ig_ = sigmoidf_(A0[r]);
                float fg_ = sigmoidf_(A1[r]);
                float gg_ = tanhf_(A2[r]);
                float og_ = sigmoidf_(A3[r]);
                float c   = fg_ * creg[r] + ig_ * gg_;
                creg[r]   = c;
                float h   = og_ * tanhf_(c);
                hreg[r]   = h;
                int m = wave * 16 + quad * 4 + r;
                hstage[m][col] = f2bf(h);
            }
            __syncthreads();                        // hstage complete
            unsigned short* hout = hring
                + (size_t)((role == 1) ? (t & 3) : (t & 1)) * BD;
            if (wave == 0) {                        // fragment-layout write
                const unsigned long long* src = (const unsigned long long*)&hstage[lane][0];
                unsigned long long v0 = src[0], v1 = src[1], v2 = src[2], v3 = src[3];
                unsigned short* dst = hout + (size_t)kcp * 2048 + (size_t)lane * 32 + sub;
                coh_store8(dst + 0,  v0);
                coh_store8(dst + 4,  v1);
                coh_store8(dst + 8,  v2);
                coh_store8(dst + 12, v3);
                asm volatile("s_waitcnt vmcnt(0)" ::: "memory");  // wave-level drain
                if (tid == 0) publish(role, ug, t + 1);
            }

            // off-critical-path output stores
            if (role == 3) {
                #pragma unroll
                for (int r = 0; r < 4; ++r) {
                    int m = wave * 16 + quad * 4 + r;
                    out[(size_t)t * BD + (size_t)m * DIM + ub + col] = hreg[r];
                    if (t == T_STEPS - 1) {
                        out[(size_t)T_STEPS * BD + 1 * BD + m * DIM + ub + col] = hreg[r];
                        out[(size_t)T_STEPS * BD + 3 * BD + m * DIM + ub + col] = creg[r];
                    }
                }
            } else if (t == T_STEPS - 1) {
                #pragma unroll
                for (int r = 0; r < 4; ++r) {
                    int m = wave * 16 + quad * 4 + r;
                    out[(size_t)T_STEPS * BD + 0 * BD + m * DIM + ub + col] = hreg[r];
                    out[(size_t)T_STEPS * BD + 2 * BD + m * DIM + ub + col] = creg[r];
                }
            }
        }
    }
}

extern "C" void kernel_launch(void* const* d_in, const int* in_sizes, int n_in,
                              void* d_out, int out_size, void* d_ws, size_t ws_size,
                              hipStream_t stream) {
    const float* x     = (const float*)d_in[0];
    const float* hx    = (const float*)d_in[1];
    const float* cx    = (const float*)d_in[2];
    const float* w_ih0 = (const float*)d_in[3];
    const float* w_hh0 = (const float*)d_in[4];
    const float* b_ih0 = (const float*)d_in[5];
    const float* b_hh0 = (const float*)d_in[6];
    const float* w_ih1 = (const float*)d_in[7];
    const float* w_hh1 = (const float*)d_in[8];
    const float* b_ih1 = (const float*)d_in[9];
    const float* b_hh1 = (const float*)d_in[10];
    float* outp = (float*)d_out;
    unsigned short* wsp = (unsigned short*)d_ws;

    void* args[] = { &x, &hx, &cx, &w_ih0, &w_hh0, &b_ih0, &b_hh0,
                     &w_ih1, &w_hh1, &b_ih1, &b_hh1, &outp, &wsp };
    hipLaunchCooperativeKernel((void*)lstm_fused, dim3(256), dim3(256),
                               args, 0, stream);
}

// Round 15
// 3530.083 us; speedup vs baseline: 2.8737x; 1.1348x over previous
//
#include <hip/hip_runtime.h>
#include <hip/hip_bf16.h>
#include <hip/hip_cooperative_groups.h>
#include <cstddef>

namespace cg = cooperative_groups;

typedef short bf16x8 __attribute__((ext_vector_type(8)));
typedef float f32x4 __attribute__((ext_vector_type(4)));

#define T_STEPS 512
#define BATCH   64
#define DIM     1024
#define BD      (BATCH*DIM)                   // 65536
#define XB_ELEMS ((size_t)T_STEPS*BATCH*DIM)  // 33554432
#define IGSLOT  262144                        // f32 per ig ring slot (64ug*4096)
#define FSTRIDE 16                            // flag stride in uints (64B)

__device__ __forceinline__ float sigmoidf_(float x) { return 1.f / (1.f + __expf(-x)); }
__device__ __forceinline__ float tanhf_(float x)    { return 2.f / (1.f + __expf(-2.f * x)) - 1.f; }
__device__ __forceinline__ unsigned short f2bf(float f) {
    union { float f; unsigned int u; } v; v.f = f;
    unsigned int u = v.u + 0x7fffu + ((v.u >> 16) & 1u);
    return (unsigned short)(u >> 16);
}

// proven coherent (agent-scope, L1/L2-bypassing) 8B primitives
__device__ __forceinline__ unsigned long long coh_load8(const void* p) {
    return __hip_atomic_load((const unsigned long long*)p,
                             __ATOMIC_RELAXED, __HIP_MEMORY_SCOPE_AGENT);
}
__device__ __forceinline__ void coh_store8(void* p, unsigned long long v) {
    __hip_atomic_store((unsigned long long*)p, v,
                       __ATOMIC_RELAXED, __HIP_MEMORY_SCOPE_AGENT);
}

// 256 blocks x 512 threads (8 waves: 2/SIMD for TLP latency hiding).
// Roles of 64 blocks (ug = unit-group, 16 units each):
// role0 l0-inp: ig0[t] = W_ih0 @ xb[t] + biases0
// role1 l0-rec: h0[t]  = lstm(W_hh0 @ h0[t-1] + ig0[t])
// role2 l1-inp: ig1[t] = W_ih1 @ h0[t] + biases1
// role3 l1-rec: h1[t]  = lstm(W_hh1 @ h1[t-1] + ig1[t]) -> out
// K-SPLIT: waves 0-3 (kw=0) do K-chunks 0..15, waves 4-7 (kw=1) chunks 16..31;
// partial sums combined in LDS. h slots stored FRAGMENT-MAJOR:
// element (row m, dim d) at (d>>5)*2048 + m*32 + (d&31).
__global__ void __launch_bounds__(512, 2)
lstm_fused(const float* __restrict__ x,
           const float* __restrict__ hx,
           const float* __restrict__ cx,
           const float* __restrict__ w_ih0, const float* __restrict__ w_hh0,
           const float* __restrict__ b_ih0, const float* __restrict__ b_hh0,
           const float* __restrict__ w_ih1, const float* __restrict__ w_hh1,
           const float* __restrict__ b_ih1, const float* __restrict__ b_hh1,
           float* __restrict__ out,
           unsigned short* __restrict__ ws)
{
    unsigned short* xb = ws;
    unsigned short* h0 = ws + XB_ELEMS;
    unsigned short* h1 = h0 + 4 * BD;
    float* ig0 = (float*)(h1 + 2 * BD);
    float* ig1 = ig0 + 2 * IGSLOT;
    unsigned* flags = (unsigned*)(ig1 + 2 * IGSLOT);

    const int tid  = threadIdx.x;
    const int lane = tid & 63;
    const int wave = tid >> 6;          // 0..7
    const int kw   = wave >> 2;         // K-half
    const int mw   = wave & 3;          // M quarter (rows mw*16..mw*16+15)
    const int bid  = blockIdx.x;
    const int role = bid >> 6;          // 0..3
    const int ug   = bid & 63;
    const int ub   = ug * 16;

    __shared__ __align__(16) unsigned short wB[65536];      // 128 KB weights
    __shared__ __align__(16) unsigned short hstage[64][16]; // 2 KB h repack
    __shared__ __align__(16) f32x4 red[4][4][64];           // 16 KB K-reduction

    // ---- stage this role's weight matrix into LDS (fragment order) ----
    {
        const float* wm = (role == 0) ? w_ih0 : (role == 1) ? w_hh0
                        : (role == 2) ? w_ih1 : w_hh1;
        for (int idx = tid; idx < 8192; idx += 512) {
            int l  = idx & 63;
            int kc = (idx >> 6) & 31;
            int n  = idx >> 11;
            int c  = l & 15, kq = l >> 4;
            const float* src = wm + (size_t)(n * DIM + ub + c) * DIM + kc * 32 + kq * 8;
            float4 v0 = *(const float4*)(src);
            float4 v1 = *(const float4*)(src + 4);
            unsigned short o[8];
            o[0]=f2bf(v0.x); o[1]=f2bf(v0.y); o[2]=f2bf(v0.z); o[3]=f2bf(v0.w);
            o[4]=f2bf(v1.x); o[5]=f2bf(v1.y); o[6]=f2bf(v1.z); o[7]=f2bf(v1.w);
            *(bf16x8*)(&wB[(size_t)idx * 8]) = *(const bf16x8*)o;
        }
    }

    // ---- cast x to bf16 (grid-stride; xb row-major) ----
    {
        const int nthr = 512 * gridDim.x;
        const int gtid = bid * 512 + tid;
        const float4* xv = (const float4*)x;
        const int n4 = (int)(XB_ELEMS / 4);
        for (int i = gtid; i < n4; i += nthr) {
            float4 v = xv[i];
            ushort4 o;
            o.x=f2bf(v.x); o.y=f2bf(v.y); o.z=f2bf(v.z); o.w=f2bf(v.w);
            *(ushort4*)(xb + (size_t)i * 4) = o;
        }
    }

    // ---- h[-1] into ring, fragment layout (l0: slot 3; l1: slot 1) ----
    if (role == 1 || role == 3) {
        unsigned short* hdst = (role == 1) ? (h0 + 3 * BD) : (h1 + 1 * BD);
        const float* hsrc = hx + (size_t)(role >> 1) * BD;
        const int kcp0 = ub >> 5, sub0 = ub & 31;
        for (int e = tid; e < 1024; e += 512) {
            int row = e >> 4, uu = e & 15;
            hdst[kcp0 * 2048 + row * 32 + sub0 + uu] = f2bf(hsrc[row * DIM + ub + uu]);
        }
    }

    if (tid == 0)
        __hip_atomic_store(flags + (size_t)((role << 6) | ug) * FSTRIDE, 0u,
                           __ATOMIC_RELAXED, __HIP_MEMORY_SCOPE_AGENT);

    const int col  = lane & 15;
    const int quad = lane >> 4;

    // biases (producer roles, kw0 only — avoids double-count across K-halves)
    float biasv[4] = {0.f, 0.f, 0.f, 0.f};
    if ((role == 0 || role == 2) && kw == 0) {
        const float* bi = (role == 0) ? b_ih0 : b_ih1;
        const float* bh = (role == 0) ? b_hh0 : b_hh1;
        #pragma unroll
        for (int n = 0; n < 4; ++n) {
            int row = n * DIM + ub + col;
            biasv[n] = bi[row] + bh[row];
        }
    }

    // c-state (rec roles, kw0 waves own the output rows)
    float creg[4] = {0.f, 0.f, 0.f, 0.f};
    if ((role == 1 || role == 3) && kw == 0) {
        const float* csrc = cx + (size_t)(role >> 1) * BD;
        #pragma unroll
        for (int r = 0; r < 4; ++r) {
            int m = mw * 16 + quad * 4 + r;
            creg[r] = csrc[m * DIM + ub + col];
        }
    }

    cg::grid_group grid = cg::this_grid();
    __syncthreads();
    grid.sync();

    const int arow = mw * 16 + col;     // A-fragment batch row
    const int kc0  = kw * 16;           // this wave's K-chunk base

    auto poll_ge = [&](const unsigned* f, int target) {
        while ((int)__hip_atomic_load(f, __ATOMIC_RELAXED, __HIP_MEMORY_SCOPE_AGENT) < target)
            __builtin_amdgcn_s_sleep(1);
    };
    auto Fp = [&](int set, int idx) -> unsigned* {
        return flags + (size_t)((set << 6) | idx) * FSTRIDE;
    };
    auto publish = [&](int set, int idx, int val) {
        __hip_atomic_store(Fp(set, idx), (unsigned)val,
                           __ATOMIC_RELAXED, __HIP_MEMORY_SCOPE_AGENT);
    };

    // plain-load half-GEMM (cached xb, row-major): 16 chunks from kc0
    auto gemm_plain = [&](const unsigned short* Ap,
                          f32x4& A0, f32x4& A1, f32x4& A2, f32x4& A3) {
        const unsigned short* Abase = Ap + (size_t)arow * DIM + quad * 8 + kc0 * 32;
        #pragma unroll 8
        for (int k2 = 0; k2 < 16; ++k2) {
            int kc = kc0 + k2;
            bf16x8 a  = *(const bf16x8*)(Abase + k2 * 32);
            bf16x8 b0 = *(const bf16x8*)(&wB[((size_t)(0*32 + kc)*64 + lane)*8]);
            bf16x8 b1 = *(const bf16x8*)(&wB[((size_t)(1*32 + kc)*64 + lane)*8]);
            bf16x8 b2 = *(const bf16x8*)(&wB[((size_t)(2*32 + kc)*64 + lane)*8]);
            bf16x8 b3 = *(const bf16x8*)(&wB[((size_t)(3*32 + kc)*64 + lane)*8]);
            A0 = __builtin_amdgcn_mfma_f32_16x16x32_bf16(a, b0, A0, 0, 0, 0);
            A1 = __builtin_amdgcn_mfma_f32_16x16x32_bf16(a, b1, A1, 0, 0, 0);
            A2 = __builtin_amdgcn_mfma_f32_16x16x32_bf16(a, b2, A2, 0, 0, 0);
            A3 = __builtin_amdgcn_mfma_f32_16x16x32_bf16(a, b3, A3, 0, 0, 0);
        }
    };

    // coherent half-GEMM on FRAGMENT-MAJOR h: 16 chunks, pre[8] rolling window
    // (R9/R13-proven register footprint). Optional ig preload into acc (kw0).
    auto gemm_coh = [&](const unsigned short* Ap, const float* igb,
                        f32x4& A0, f32x4& A1, f32x4& A2, f32x4& A3) {
        const unsigned short* Abase = Ap + (size_t)arow * 32 + quad * 8
                                    + (size_t)kc0 * 2048;
        if (igb) {
            union { f32x4 v; unsigned long long q[2]; } g0, g1, g2, g3;
            g0.q[0] = coh_load8(igb + 0*128); g0.q[1] = coh_load8(igb + 1*128);
            g1.q[0] = coh_load8(igb + 2*128); g1.q[1] = coh_load8(igb + 3*128);
            g2.q[0] = coh_load8(igb + 4*128); g2.q[1] = coh_load8(igb + 5*128);
            g3.q[0] = coh_load8(igb + 6*128); g3.q[1] = coh_load8(igb + 7*128);
            A0 = g0.v; A1 = g1.v; A2 = g2.v; A3 = g3.v;
        }
        union U { bf16x8 v; unsigned long long q[2]; };
        U pre[8];
        #pragma unroll
        for (int i = 0; i < 8; ++i) {
            pre[i].q[0] = coh_load8(Abase + (size_t)i * 2048);
            pre[i].q[1] = coh_load8(Abase + (size_t)i * 2048 + 4);
        }
        #pragma unroll
        for (int k2 = 0; k2 < 16; ++k2) {
            U cur = pre[k2 & 7];
            if (k2 < 8) {
                pre[k2 & 7].q[0] = coh_load8(Abase + (size_t)(k2 + 8) * 2048);
                pre[k2 & 7].q[1] = coh_load8(Abase + (size_t)(k2 + 8) * 2048 + 4);
            }
            int kc = kc0 + k2;
            bf16x8 b0 = *(const bf16x8*)(&wB[((size_t)(0*32 + kc)*64 + lane)*8]);
            bf16x8 b1 = *(const bf16x8*)(&wB[((size_t)(1*32 + kc)*64 + lane)*8]);
            bf16x8 b2 = *(const bf16x8*)(&wB[((size_t)(2*32 + kc)*64 + lane)*8]);
            bf16x8 b3 = *(const bf16x8*)(&wB[((size_t)(3*32 + kc)*64 + lane)*8]);
            A0 = __builtin_amdgcn_mfma_f32_16x16x32_bf16(cur.v, b0, A0, 0, 0, 0);
            A1 = __builtin_amdgcn_mfma_f32_16x16x32_bf16(cur.v, b1, A1, 0, 0, 0);
            A2 = __builtin_amdgcn_mfma_f32_16x16x32_bf16(cur.v, b2, A2, 0, 0, 0);
            A3 = __builtin_amdgcn_mfma_f32_16x16x32_bf16(cur.v, b3, A3, 0, 0, 0);
        }
    };

    // K-reduction: kw1 publishes partials to LDS; kw0 accumulates.
    auto k_reduce = [&](f32x4& A0, f32x4& A1, f32x4& A2, f32x4& A3) {
        if (kw) {
            red[0][mw][lane] = A0; red[1][mw][lane] = A1;
            red[2][mw][lane] = A2; red[3][mw][lane] = A3;
        }
        __syncthreads();
        if (!kw) {
            A0 += red[0][mw][lane]; A1 += red[1][mw][lane];
            A2 += red[2][mw][lane]; A3 += red[3][mw][lane];
        }
    };

    // producer tail: kw0 dumps ig (wave-contiguous layout) + publish
    auto dump_ig = [&](float* slot, int set, int t,
                       f32x4 A0, f32x4 A1, f32x4 A2, f32x4 A3) {
        if (!kw) {
            float* base = slot + (size_t)ug * 4096 + (size_t)mw * 1024 + lane * 2;
            union { f32x4 v; unsigned long long q[2]; } u0, u1, u2, u3;
            u0.v = A0; u1.v = A1; u2.v = A2; u3.v = A3;
            coh_store8(base + 0*128, u0.q[0]); coh_store8(base + 1*128, u0.q[1]);
            coh_store8(base + 2*128, u1.q[0]); coh_store8(base + 3*128, u1.q[1]);
            coh_store8(base + 4*128, u2.q[0]); coh_store8(base + 5*128, u2.q[1]);
            coh_store8(base + 6*128, u3.q[0]); coh_store8(base + 7*128, u3.q[1]);
        }
        asm volatile("s_waitcnt vmcnt(0)" ::: "memory");
        __syncthreads();
        if (tid == 0) publish(set, ug, t + 1);
    };

    const int kcp = ub >> 5, sub = ub & 31;

    for (int t = 0; t < T_STEPS; ++t) {
        f32x4 A0 = {0,0,0,0}, A1 = {0,0,0,0}, A2 = {0,0,0,0}, A3 = {0,0,0,0};

        if (role == 0) {            // ---------- l0-inp ----------
            if (tid == 0) poll_ge(Fp(1, ug), t - 1);
            __syncthreads();
            if (!kw) {
                A0 = f32x4{biasv[0], biasv[0], biasv[0], biasv[0]};
                A1 = f32x4{biasv[1], biasv[1], biasv[1], biasv[1]};
                A2 = f32x4{biasv[2], biasv[2], biasv[2], biasv[2]};
                A3 = f32x4{biasv[3], biasv[3], biasv[3], biasv[3]};
            }
            gemm_plain(xb + (size_t)t * BD, A0, A1, A2, A3);
            k_reduce(A0, A1, A2, A3);
            dump_ig(ig0 + (size_t)(t & 1) * IGSLOT, 0, t, A0, A1, A2, A3);

        } else if (role == 2) {     // ---------- l1-inp ----------
            if (tid < 64) poll_ge(Fp(1, tid), t + 1);
            else if (tid == 64) poll_ge(Fp(3, ug), t - 1);
            __syncthreads();
            if (!kw) {
                A0 = f32x4{biasv[0], biasv[0], biasv[0], biasv[0]};
                A1 = f32x4{biasv[1], biasv[1], biasv[1], biasv[1]};
                A2 = f32x4{biasv[2], biasv[2], biasv[2], biasv[2]};
                A3 = f32x4{biasv[3], biasv[3], biasv[3], biasv[3]};
            }
            gemm_coh(h0 + (size_t)(t & 3) * BD, nullptr, A0, A1, A2, A3);
            k_reduce(A0, A1, A2, A3);
            dump_ig(ig1 + (size_t)(t & 1) * IGSLOT, 2, t, A0, A1, A2, A3);

        } else {                    // ---------- rec roles ----------
            if (role == 1) {
                if (tid < 64) poll_ge(Fp(1, tid), t);
                else if (tid < 128) poll_ge(Fp(2, tid - 64), t - 3);
                else if (tid == 128) poll_ge(Fp(0, ug), t + 1);
            } else {
                if (tid < 64) poll_ge(Fp(3, tid), t);
                else if (tid == 64) poll_ge(Fp(2, ug), t + 1);
            }
            __syncthreads();

            unsigned short* hring = (role == 1) ? h0 : h1;
            const unsigned short* hsrc = (role == 1)
                ? (h0 + (size_t)((t - 1) & 3) * BD)
                : (h1 + (size_t)((t - 1) & 1) * BD);
            const float* igb = (!kw)
                ? ((role == 1) ? ig0 : ig1) + (size_t)(t & 1) * IGSLOT
                  + (size_t)ug * 4096 + (size_t)mw * 1024 + lane * 2
                : nullptr;
            gemm_coh(hsrc, igb, A0, A1, A2, A3);
            k_reduce(A0, A1, A2, A3);

            float hreg[4] = {0.f, 0.f, 0.f, 0.f};
            if (!kw) {
                #pragma unroll
                for (int r = 0; r < 4; ++r) {
                    float ig_ = sigmoidf_(A0[r]);
                    float fg_ = sigmoidf_(A1[r]);
                    float gg_ = tanhf_(A2[r]);
                    float og_ = sigmoidf_(A3[r]);
                    float c   = fg_ * creg[r] + ig_ * gg_;
                    creg[r]   = c;
                    float h   = og_ * tanhf_(c);
                    hreg[r]   = h;
                    int m = mw * 16 + quad * 4 + r;
                    hstage[m][col] = f2bf(h);
                }
            }
            __syncthreads();                        // hstage complete
            unsigned short* hout = hring
                + (size_t)((role == 1) ? (t & 3) : (t & 1)) * BD;
            if (wave == 0) {                        // fragment-layout write
                const unsigned long long* src = (const unsigned long long*)&hstage[lane][0];
                unsigned long long v0 = src[0], v1 = src[1], v2 = src[2], v3 = src[3];
                unsigned short* dst = hout + (size_t)kcp * 2048 + (size_t)lane * 32 + sub;
                coh_store8(dst + 0,  v0);
                coh_store8(dst + 4,  v1);
                coh_store8(dst + 8,  v2);
                coh_store8(dst + 12, v3);
                asm volatile("s_waitcnt vmcnt(0)" ::: "memory");
                if (tid == 0) publish(role, ug, t + 1);
            }

            // off-critical-path output stores (kw0 waves hold hreg/creg)
            if (!kw) {
                if (role == 3) {
                    #pragma unroll
                    for (int r = 0; r < 4; ++r) {
                        int m = mw * 16 + quad * 4 + r;
                        out[(size_t)t * BD + (size_t)m * DIM + ub + col] = hreg[r];
                        if (t == T_STEPS - 1) {
                            out[(size_t)T_STEPS * BD + 1 * BD + m * DIM + ub + col] = hreg[r];
                            out[(size_t)T_STEPS * BD + 3 * BD + m * DIM + ub + col] = creg[r];
                        }
                    }
                } else if (t == T_STEPS - 1) {
                    #pragma unroll
                    for (int r = 0; r < 4; ++r) {
                        int m = mw * 16 + quad * 4 + r;
                        out[(size_t)T_STEPS * BD + 0 * BD + m * DIM + ub + col] = hreg[r];
                        out[(size_t)T_STEPS * BD + 2 * BD + m * DIM + ub + col] = creg[r];
                    }
                }
            }
        }
    }
}

extern "C" void kernel_launch(void* const* d_in, const int* in_sizes, int n_in,
                              void* d_out, int out_size, void* d_ws, size_t ws_size,
                              hipStream_t stream) {
    const float* x     = (const float*)d_in[0];
    const float* hx    = (const float*)d_in[1];
    const float* cx    = (const float*)d_in[2];
    const float* w_ih0 = (const float*)d_in[3];
    const float* w_hh0 = (const float*)d_in[4];
    const float* b_ih0 = (const float*)d_in[5];
    const float* b_hh0 = (const float*)d_in[6];
    const float* w_ih1 = (const float*)d_in[7];
    const float* w_hh1 = (const float*)d_in[8];
    const float* b_ih1 = (const float*)d_in[9];
    const float* b_hh1 = (const float*)d_in[10];
    float* outp = (float*)d_out;
    unsigned short* wsp = (unsigned short*)d_ws;

    void* args[] = { &x, &hx, &cx, &w_ih0, &w_hh0, &b_ih0, &b_hh0,
                     &w_ih1, &w_hh1, &b_ih1, &b_hh1, &outp, &wsp };
    hipLaunchCooperativeKernel((void*)lstm_fused, dim3(256), dim3(512),
                               args, 0, stream);
}